// Round 6
// baseline (771.220 us; speedup 1.0000x reference)
//
#include <hip/hip_runtime.h>

#define T_STEPS 256
#define B_ROWS  1024
#define NX_ 256
#define NY_ 64
#define NU_ 64
#define ND_ 32

#define CHUNK   32
#define NCHUNK  8          // T_STEPS / CHUNK

typedef _Float16 half8  __attribute__((ext_vector_type(8)));
typedef _Float16 half4v __attribute__((ext_vector_type(4)));
typedef float    f32x4  __attribute__((ext_vector_type(4)));

#define MFMA16(a,b,c) __builtin_amdgcn_mfma_f32_16x16x32_f16((a),(b),(c),0,0,0)

#define XPITCH 264              // padded LDS row pitch (halfs) for x-buffer
#define XBUFSZ (16*XPITCH)

// U/D staging tiles (f16, double-buffered), cooperative (R5: -21%).
#define UP 72
#define DP 40
#define UBUFH (16*UP)
#define DBUFH (16*DP)

// lgkmcnt-only barrier (R4: -9%). Global stores/loads stay in flight.
__device__ __forceinline__ void block_sync_lds() {
  asm volatile("s_waitcnt lgkmcnt(0)" ::: "memory");
  __builtin_amdgcn_s_barrier();
  asm volatile("" ::: "memory");
}

__device__ __forceinline__ half4v cvt4(f32x4 a) {
  half4v h;
  h[0]=(_Float16)a[0]; h[1]=(_Float16)a[1]; h[2]=(_Float16)a[2]; h[3]=(_Float16)a[3];
  return h;
}

// ---------------------------------------------------------------------------
// out = in @ in (256x256 f32). from_wx: in-matrix is M = Wx^T read from Wx.
// ---------------------------------------------------------------------------
extern "C" __global__ __launch_bounds__(256)
void matsq(const float* __restrict__ src, float* __restrict__ dst, int from_wx)
{
  const int r = blockIdx.x, c = threadIdx.x;
  float acc = 0.f;
  if (from_wx) {
    for (int k = 0; k < NX_; k++) acc += src[k*NX_ + r] * src[c*NX_ + k];
  } else {
    for (int k = 0; k < NX_; k++) acc += src[r*NX_ + k] * src[k*NX_ + c];
  }
  dst[r*NX_ + c] = acc;
}

// ---------------------------------------------------------------------------
// Phase 1: 1024 threads / 16 waves, each wave owns 16 output columns (nt=1).
// R5 ran 8 waves x 32 cols: the 152+ operand regs/thread (Wx hi/lo frags)
// pushed unified V+A use to ~192 -> only 2 waves/SIMD resident (occupancy
// ~23%, 62% latency-exposed). Halving the per-wave tile halves operand regs
// (~76) -> 4 waves/SIMD. Same total MFMA work per CU per step.
// ---------------------------------------------------------------------------
extern "C" __global__ __launch_bounds__(1024)
void phase1(const float* __restrict__ x0,
            const float* __restrict__ U,
            const float* __restrict__ Dd,
            const float* __restrict__ Wx,
            const float* __restrict__ bx,
            const float* __restrict__ Wu,
            const float* __restrict__ bu,
            const float* __restrict__ Wd,
            const float* __restrict__ bd,
            float* __restrict__ Lend)
{
  __shared__ __align__(16) _Float16 xb[2*XBUFSZ];
  __shared__ __align__(16) _Float16 ub[2*UBUFH];
  __shared__ __align__(16) _Float16 db[2*DBUFH];

  const int tid  = threadIdx.x;
  const int lane = tid & 63;
  const int w    = tid >> 6;           // 0..15
  const int q    = lane >> 4;
  const int n16  = lane & 15;
  const int b0   = blockIdx.x * 16;
  const int ck   = blockIdx.y;          // chunk 0..6
  const int t0   = ck * CHUNK;
  const int c0   = w * 16;              // 16 cols per wave

  // staging roles: threads 0..255 -> U tile (16x64), 256..383 -> D (16x32)
  const bool isU = (tid < 256);
  const bool isD = (tid >= 256) && (tid < 384);
  const int  srow = isU ? (tid >> 4) : ((tid - 256) >> 3);
  const int  sch  = isU ? (tid & 15) : ((tid - 256) & 7);
  const float* sgbase = isU ? (U  + (size_t)(b0 + srow)*NU_ + sch*4)
                            : (Dd + (size_t)(b0 + srow)*ND_ + sch*4);
  const size_t sstep  = (size_t)B_ROWS * (isU ? NU_ : ND_);
  _Float16* sldsbase  = isU ? (ub + srow*UP + sch*4) : (db + srow*DP + sch*4);
  const int  sbufstep = isU ? UBUFH : DBUFH;

  // ---- stage init state into xb[0] ----
  if (ck == 0) {
    for (int i = tid; i < 16*32; i += 1024) {
      int row = i >> 5, ch = i & 31;
      const float* s = x0 + (size_t)(b0+row)*NX_ + ch*8;
      _Float16* dst = &xb[row*XPITCH + ch*8];
      #pragma unroll
      for (int j=0;j<8;j++) dst[j] = (_Float16)s[j];
    }
  } else {
    for (int i = tid; i < XBUFSZ; i += 1024) xb[i] = (_Float16)0.f;
  }

  // ---- stage U/D for t0 into buf 0 ----
  if (isU || isD) {
    f32x4 v = *(const f32x4*)(sgbase + (size_t)t0*sstep);
    *(half4v*)sldsbase = cvt4(v);
  }

  // ---- Wx hi/lo B-frags (16 cols per wave) ----
  half8 Wh[8], Wl[8];
  {
    const int row = c0 + n16;
    #pragma unroll
    for (int kk=0; kk<8; kk++) {
      const float* s = Wx + row*NX_ + kk*32 + q*8;
      half8 h, l;
      #pragma unroll
      for (int j=0;j<8;j++){
        float v = s[j];
        _Float16 hi = (_Float16)v;
        h[j] = hi;
        l[j] = (_Float16)(v - (float)hi);
      }
      Wh[kk]=h; Wl[kk]=l;
    }
  }
  half8 WuF[2];
  {
    const int row=c0+n16;
    #pragma unroll
    for(int kk=0;kk<2;kk++){
      const float* s=Wu+row*NU_+kk*32+q*8; half8 h;
      #pragma unroll
      for(int j=0;j<8;j++) h[j]=(_Float16)s[j];
      WuF[kk]=h;
    }
  }
  half8 WdF;
  {
    const int row=c0+n16;
    const float* s=Wd+row*ND_+q*8;
    #pragma unroll
    for(int j=0;j<8;j++) WdF[j]=(_Float16)s[j];
  }
  const float bxs = bx[c0+n16];
  const float bus = bu[c0+n16];
  const float bds = bd[c0+n16];

  float xcv[4];
  #pragma unroll
  for(int r=0;r<4;r++)
    xcv[r] = (ck==0) ? x0[(size_t)(b0+q*4+r)*NX_ + c0+n16] : 0.f;

  block_sync_lds();

  for (int tt=0; tt<CHUNK; tt++) {
    const int cur = tt&1;
    const _Float16* xr = xb + cur*XBUFSZ;
    _Float16*       xw = xb + (cur^1)*XBUFSZ;

    // (A) prefetch next step's U/D tile into 4 regs
    f32x4 pre;
    {
      const int tn = (tt+1 < CHUNK) ? (t0+tt+1) : (t0+tt);
      if (isU || isD) pre = *(const f32x4*)(sgbase + (size_t)tn*sstep);
    }

    // (B) frag reads from LDS
    const _Float16* ubr = ub + cur*UBUFH;
    const _Float16* dbr = db + cur*DBUFH;
    half8 uf0 = *(const half8*)(ubr + n16*UP + q*8);
    half8 uf1 = *(const half8*)(ubr + n16*UP + 32 + q*8);
    half8 df  = *(const half8*)(dbr + n16*DP + q*8);

    // hi/lo in SEPARATE accumulators: 2 independent 8-chains (ILP)
    f32x4 xnh = (f32x4){bxs,bxs,bxs,bxs};
    f32x4 xnl = (f32x4){0.f,0.f,0.f,0.f};
    #pragma unroll
    for (int kk=0;kk<8;kk++){
      half8 xa = *(const half8*)(xr + n16*XPITCH + kk*32 + q*8);
      xnh = MFMA16(xa, Wh[kk], xnh);
      xnl = MFMA16(xa, Wl[kk], xnl);
    }

    f32x4 fu = (f32x4){bus,bus,bus,bus};
    f32x4 fd = (f32x4){bds,bds,bds,bds};
    fu = MFMA16(uf0, WuF[0], fu);
    fu = MFMA16(uf1, WuF[1], fu);
    fd = MFMA16(df,  WdF,    fd);

    #pragma unroll
    for (int r=0;r<4;r++){
      float z = xnh[r] + xnl[r] + fu[r] + fd[r];
      xw[(q*4+r)*XPITCH + c0+n16] = (_Float16)z;
      xcv[r] = z;
    }

    // (C) publish prefetched tile
    if (isU || isD) *(half4v*)(sldsbase + (cur^1)*sbufstep) = cvt4(pre);

    block_sync_lds();
  }

  // store chunk-final state
  float* dst = Lend + (size_t)ck*(B_ROWS*NX_);
  #pragma unroll
  for (int r=0;r<4;r++)
    dst[(size_t)(b0+q*4+r)*NX_ + c0+n16] = xcv[r];
}

// ---------------------------------------------------------------------------
// Combine: S[1] = Lend[0]; S[k] = S[k-1] @ P + Lend[k-1], k = 2..7.
// ---------------------------------------------------------------------------
extern "C" __global__ __launch_bounds__(512)
void combine(const float* __restrict__ P,
             const float* __restrict__ Lend,
             float* __restrict__ S)
{
  __shared__ __align__(16) _Float16 xb[2*XBUFSZ];

  const int tid  = threadIdx.x;
  const int lane = tid & 63;
  const int w    = tid >> 6;
  const int q    = lane >> 4;
  const int n16  = lane & 15;
  const int b0   = blockIdx.x * 16;
  const int c0   = w * 32;
  const size_t BN = (size_t)B_ROWS*NX_;

  half8 Ph[2][8], Pl[2][8];
  #pragma unroll
  for (int nt=0; nt<2; nt++) {
    const int n = c0 + nt*16 + n16;
    #pragma unroll
    for (int kk=0; kk<8; kk++) {
      half8 h, l;
      #pragma unroll
      for (int j=0;j<8;j++){
        float v = P[(size_t)(kk*32 + q*8 + j)*NX_ + n];
        _Float16 hi = (_Float16)v;
        h[j] = hi;
        l[j] = (_Float16)(v - (float)hi);
      }
      Ph[nt][kk]=h; Pl[nt][kk]=l;
    }
  }

  {
    int row = tid >> 5, ch = tid & 31;
    const float* s = Lend + (size_t)(b0+row)*NX_ + ch*8;
    float*       o = S    + (size_t)(b0+row)*NX_ + ch*8;
    _Float16* dst = &xb[row*XPITCH + ch*8];
    #pragma unroll
    for (int j=0;j<8;j++){ float v = s[j]; dst[j] = (_Float16)v; o[j] = v; }
  }
  block_sync_lds();

  for (int k=2; k<=7; k++) {
    const int rp = (k-2)&1;
    const _Float16* xr = xb + rp*XBUFSZ;
    _Float16*       xw = xb + (rp^1)*XBUFSZ;

    const float* lsrc = Lend + (size_t)(k-1)*BN;
    f32x4 xn[2];
    #pragma unroll
    for (int nt=0;nt<2;nt++)
      #pragma unroll
      for (int r=0;r<4;r++)
        xn[nt][r] = lsrc[(size_t)(b0+q*4+r)*NX_ + c0+nt*16+n16];

    #pragma unroll
    for (int kk=0;kk<8;kk++){
      half8 xa = *(const half8*)(xr + n16*XPITCH + kk*32 + q*8);
      xn[0] = MFMA16(xa, Ph[0][kk], xn[0]);
      xn[1] = MFMA16(xa, Ph[1][kk], xn[1]);
      xn[0] = MFMA16(xa, Pl[0][kk], xn[0]);
      xn[1] = MFMA16(xa, Pl[1][kk], xn[1]);
    }

    float* sdst = S + (size_t)(k-1)*BN;
    #pragma unroll
    for (int nt=0;nt<2;nt++)
      #pragma unroll
      for (int r=0;r<4;r++){
        float z = xn[nt][r];
        sdst[(size_t)(b0+q*4+r)*NX_ + c0+nt*16+n16] = z;
        xw[(q*4+r)*XPITCH + c0+nt*16+n16] = (_Float16)z;
      }
    block_sync_lds();
  }
}

// ---------------------------------------------------------------------------
// Phase 2: 1024 threads / 16 waves / nt=1 (see phase1 header comment).
// ---------------------------------------------------------------------------
extern "C" __global__ __launch_bounds__(1024)
void phase2(const float* __restrict__ x0,
            const float* __restrict__ U,
            const float* __restrict__ Dd,
            const float* __restrict__ Wx,
            const float* __restrict__ bx,
            const float* __restrict__ Wu,
            const float* __restrict__ bu,
            const float* __restrict__ Wd,
            const float* __restrict__ bd,
            const float* __restrict__ Wy,
            const float* __restrict__ by,
            const float* __restrict__ S,
            float* __restrict__ Xout,
            float* __restrict__ Yout,
            float* __restrict__ Rout)
{
  __shared__ __align__(16) _Float16 xb[2*XBUFSZ];
  __shared__ __align__(16) _Float16 wyl[64*XPITCH];
  __shared__ __align__(16) _Float16 ub[2*UBUFH];
  __shared__ __align__(16) _Float16 db[2*DBUFH];
  __shared__ float red[16*8];

  const int tid  = threadIdx.x;
  const int lane = tid & 63;
  const int w    = tid >> 6;           // 0..15
  const int q    = lane >> 4;
  const int n16  = lane & 15;
  const int b0   = blockIdx.x * 16;
  const int ck   = blockIdx.y;
  const int t0   = ck * CHUNK;
  const int c0   = w * 16;

  const float* init = (ck==0) ? x0 : (S + (size_t)(ck-1)*B_ROWS*NX_);

  const bool isU = (tid < 256);
  const bool isD = (tid >= 256) && (tid < 384);
  const int  srow = isU ? (tid >> 4) : ((tid - 256) >> 3);
  const int  sch  = isU ? (tid & 15) : ((tid - 256) & 7);
  const float* sgbase = isU ? (U  + (size_t)(b0 + srow)*NU_ + sch*4)
                            : (Dd + (size_t)(b0 + srow)*ND_ + sch*4);
  const size_t sstep  = (size_t)B_ROWS * (isU ? NU_ : ND_);
  _Float16* sldsbase  = isU ? (ub + srow*UP + sch*4) : (db + srow*DP + sch*4);
  const int  sbufstep = isU ? UBUFH : DBUFH;

  for (int i = tid; i < 64*32; i += 1024) {
    int row = i >> 5, ch = i & 31;
    const float* s = Wy + row*NX_ + ch*8;
    _Float16* dst = &wyl[row*XPITCH + ch*8];
    #pragma unroll
    for (int j=0;j<8;j++) dst[j] = (_Float16)s[j];
  }
  for (int i = tid; i < 16*32; i += 1024) {
    int row = i >> 5, ch = i & 31;
    const float* s = init + (size_t)(b0+row)*NX_ + ch*8;
    _Float16* dst = &xb[row*XPITCH + ch*8];
    #pragma unroll
    for (int j=0;j<8;j++) dst[j] = (_Float16)s[j];
  }
  // stage U/D for t0 into buf 0
  if (isU || isD) {
    f32x4 v = *(const f32x4*)(sgbase + (size_t)t0*sstep);
    *(half4v*)sldsbase = cvt4(v);
  }

  half8 Wh[8], Wl[8];
  {
    const int row = c0 + n16;
    #pragma unroll
    for (int kk=0; kk<8; kk++) {
      const float* s = Wx + row*NX_ + kk*32 + q*8;
      half8 h, l;
      #pragma unroll
      for (int j=0;j<8;j++){
        float v = s[j];
        _Float16 hi = (_Float16)v;
        h[j] = hi;
        l[j] = (_Float16)(v - (float)hi);
      }
      Wh[kk]=h; Wl[kk]=l;
    }
  }
  half8 WuF[2];
  {
    const int row=c0+n16;
    #pragma unroll
    for(int kk=0;kk<2;kk++){
      const float* s=Wu+row*NU_+kk*32+q*8; half8 h;
      #pragma unroll
      for(int j=0;j<8;j++) h[j]=(_Float16)s[j];
      WuF[kk]=h;
    }
  }
  half8 WdF;
  {
    const int row=c0+n16;
    const float* s=Wd+row*ND_+q*8;
    #pragma unroll
    for(int j=0;j<8;j++) WdF[j]=(_Float16)s[j];
  }
  const float bxs = bx[c0+n16];
  const float bus = bu[c0+n16];
  const float bds = bd[c0+n16];
  const float bys = (w<4) ? by[w*16+n16] : 0.f;

  float xcv[4];
  #pragma unroll
  for(int r=0;r<4;r++)
    xcv[r] = init[(size_t)(b0+q*4+r)*NX_ + c0+n16];

  // stats: 0 sxmin, 1 sxmax, 2 sumin, 3 sumax, 4 sdx, 5 dx_d.
  // dx_u == sumin+sumax pointwise -> folded as 2*(s2+s3) at the end.
  float st[6];
  #pragma unroll
  for(int i=0;i<6;i++) st[i]=0.f;

  block_sync_lds();

  for (int tt=0; tt<CHUNK; tt++) {
    const int t = t0 + tt;
    const int cur = tt&1;
    const _Float16* xr = xb + cur*XBUFSZ;
    _Float16*       xw = xb + (cur^1)*XBUFSZ;

    // (A) prefetch next step's U/D tile (4 regs)
    f32x4 pre;
    {
      const int tn = (tt+1 < CHUNK) ? (t+1) : t;
      if (isU || isD) pre = *(const f32x4*)(sgbase + (size_t)tn*sstep);
    }

    // (B) frag reads from staged LDS
    const _Float16* ubr = ub + cur*UBUFH;
    const _Float16* dbr = db + cur*DBUFH;
    half8 uf0 = *(const half8*)(ubr + n16*UP + q*8);
    half8 uf1 = *(const half8*)(ubr + n16*UP + 32 + q*8);
    half8 df  = *(const half8*)(dbr + n16*DP + q*8);

    f32x4 xnh = (f32x4){bxs,bxs,bxs,bxs};
    f32x4 xnl = (f32x4){0.f,0.f,0.f,0.f};
    #pragma unroll
    for (int kk=0;kk<8;kk++){
      half8 xa = *(const half8*)(xr + n16*XPITCH + kk*32 + q*8);
      xnh = MFMA16(xa, Wh[kk], xnh);
      xnl = MFMA16(xa, Wl[kk], xnl);
    }

    f32x4 fu = (f32x4){bus,bus,bus,bus};
    f32x4 fd = (f32x4){bds,bds,bds,bds};
    fu = MFMA16(uf0, WuF[0], fu);
    fu = MFMA16(uf1, WuF[1], fu);
    fd = MFMA16(df,  WdF,    fd);

    const size_t xrowbase = (size_t)t*(B_ROWS*NX_) + (size_t)b0*NX_;
    #pragma unroll
    for (int r=0;r<4;r++){
      float f  = fu[r];
      float g  = fd[r];
      float z  = xnh[r] + xnl[r] + f + g;
      float zc = xcv[r];
      float r0 = fmaxf(-1.f - z, 0.f);
      float r1 = fmaxf( z - 1.f, 0.f);
      float r2 = fmaxf(-1.f - f, 0.f);
      float r3 = fmaxf( f - 1.f, 0.f);
      float g0 = fmaxf(-1.f - g, 0.f);
      float g1 = fmaxf( g - 1.f, 0.f);
      float dz = z - zc;
      st[0]+=r0; st[1]+=r1; st[2]+=r2; st[3]+=r3;
      st[4]+=dz*dz; st[5]+=g0+g1;
      Xout[xrowbase + (size_t)(q*4+r)*NX_ + (c0+n16)] = z;
      xw[(q*4+r)*XPITCH + c0+n16] = (_Float16)z;
      xcv[r] = z;
    }

    // (C) publish prefetched tile
    if (isU || isD) *(half4v*)(sldsbase + (cur^1)*sbufstep) = cvt4(pre);

    block_sync_lds();

    if (w < 4) {
      f32x4 ya = (f32x4){bys,bys,bys,bys};
      #pragma unroll
      for (int kk=0;kk<8;kk++){
        half8 xa = *(const half8*)(xw + n16*XPITCH + kk*32 + q*8);
        half8 wb = *(const half8*)(&wyl[(w*16+n16)*XPITCH + kk*32 + q*8]);
        ya = MFMA16(xa, wb, ya);
      }
      const size_t ybase = (size_t)t*(B_ROWS*NY_) + (size_t)b0*NY_ + w*16 + n16;
      #pragma unroll
      for (int r=0;r<4;r++)
        Yout[ybase + (size_t)(q*4+r)*NY_] = ya[r];
    }
  }

  #pragma unroll
  for (int off=32; off>=1; off>>=1){
    #pragma unroll
    for (int i=0;i<6;i++) st[i] += __shfl_down(st[i], off, 64);
  }
  __syncthreads();
  if (lane==0){
    #pragma unroll
    for (int i=0;i<6;i++) red[w*8+i] = st[i];
  }
  __syncthreads();
  if (tid==0){
    float t[6] = {0.f,0.f,0.f,0.f,0.f,0.f};
    for (int ww=0; ww<16; ww++)
      for (int i=0;i<6;i++) t[i] += red[ww*8+i];
    float s = t[0] + t[1] + 2.f*(t[2]+t[3]) + t[4] + t[5];
    atomicAdd(Rout, s * (0.2f/67108864.0f));
  }
}

extern "C" void kernel_launch(void* const* d_in, const int* in_sizes, int n_in,
                              void* d_out, int out_size, void* d_ws, size_t ws_size,
                              hipStream_t stream)
{
  const float* x0=(const float*)d_in[0];
  const float* U =(const float*)d_in[1];
  const float* Dd=(const float*)d_in[2];
  const float* Wx=(const float*)d_in[3];
  const float* bx=(const float*)d_in[4];
  const float* Wu=(const float*)d_in[5];
  const float* bu=(const float*)d_in[6];
  const float* Wd=(const float*)d_in[7];
  const float* bd=(const float*)d_in[8];
  const float* Wy=(const float*)d_in[9];
  const float* by=(const float*)d_in[10];

  float* X = (float*)d_out;
  float* Y = X + (size_t)T_STEPS*B_ROWS*NX_;
  float* R = Y + (size_t)T_STEPS*B_ROWS*NY_;

  // workspace layout (floats)
  float* B0   = (float*)d_ws;                 // 65536
  float* B1   = B0 + 65536;                   // 65536
  float* Lend = B1 + 65536;                   // 7 * 1024*256
  float* S    = Lend + (size_t)7*B_ROWS*NX_;  // 7 * 1024*256

  hipMemsetAsync(R, 0, sizeof(float), stream);

  // P = (Wx^T)^32 via repeated squaring (f32)
  matsq<<<dim3(256), dim3(256), 0, stream>>>(Wx, B1, 1);  // M^2
  matsq<<<dim3(256), dim3(256), 0, stream>>>(B1, B0, 0);  // M^4
  matsq<<<dim3(256), dim3(256), 0, stream>>>(B0, B1, 0);  // M^8
  matsq<<<dim3(256), dim3(256), 0, stream>>>(B1, B0, 0);  // M^16
  matsq<<<dim3(256), dim3(256), 0, stream>>>(B0, B1, 0);  // M^32 -> P = B1

  phase1<<<dim3(64,7), dim3(1024), 0, stream>>>(x0,U,Dd,Wx,bx,Wu,bu,Wd,bd,Lend);
  combine<<<dim3(64), dim3(512), 0, stream>>>(B1, Lend, S);
  phase2<<<dim3(64,8), dim3(1024), 0, stream>>>(x0,U,Dd,Wx,bx,Wu,bu,Wd,bd,Wy,by,S,X,Y,R);
}